// Round 14
// baseline (218.600 us; speedup 1.0000x reference)
//
#include <hip/hip_runtime.h>
#include <hip/hip_bf16.h>
#include <stdint.h>

#define MROWS 16384   // B*S
#define KDIM  2048
#define NDIM  2048
#define LEAFD 13
#define RANKD 4

typedef __bf16 bf16x8 __attribute__((ext_vector_type(8)));
typedef float  f32x4  __attribute__((ext_vector_type(4)));

// ---------------------------------------------------------------------------
// Kernel 1: w_bf[o,i] = bf16( weight[o,i] + sum_r L0[r,o2,i2]*L1[r,o1,i1]*L2[r,o0,i0] )
// ---------------------------------------------------------------------------
__global__ void build_w_kernel(const float* __restrict__ weight,
                               const float* __restrict__ leaf,
                               __hip_bfloat16* __restrict__ wbf) {
    __shared__ float ll[3 * RANKD * LEAFD * LEAFD];
    for (int t = threadIdx.x; t < 3 * RANKD * LEAFD * LEAFD; t += blockDim.x)
        ll[t] = leaf[t];
    __syncthreads();
    int idx = blockIdx.x * blockDim.x + threadIdx.x;
    if (idx >= NDIM * KDIM) return;
    int o = idx / KDIM, i = idx % KDIM;
    int o2 = o / 169, o1 = (o / 13) % 13, o0 = o % 13;
    int i2 = i / 169, i1 = (i / 13) % 13, i0 = i % 13;
    float d = 0.f;
#pragma unroll
    for (int r = 0; r < RANKD; ++r) {
        float a = ll[( r            * LEAFD + o2) * LEAFD + i2];
        float b = ll[((RANKD   + r) * LEAFD + o1) * LEAFD + i1];
        float c = ll[((2*RANKD + r) * LEAFD + o0) * LEAFD + i0];
        d += a * b * c;
    }
    wbf[idx] = __float2bfloat16(weight[idx] + d);
}

// ---------------------------------------------------------------------------
// Kernel 2: fp32 -> bf16 conversion of activations (8 floats/thread)
// ---------------------------------------------------------------------------
__global__ void cvt_kernel(const float* __restrict__ x,
                           __hip_bfloat16* __restrict__ xb, int n) {
    long stride = (long)gridDim.x * blockDim.x * 8;
    for (long idx = ((long)blockIdx.x * blockDim.x + threadIdx.x) * 8; idx < n; idx += stride) {
        float4 v0 = *reinterpret_cast<const float4*>(x + idx);
        float4 v1 = *reinterpret_cast<const float4*>(x + idx + 4);
        __hip_bfloat16 tmp[8];
        tmp[0] = __float2bfloat16(v0.x); tmp[1] = __float2bfloat16(v0.y);
        tmp[2] = __float2bfloat16(v0.z); tmp[3] = __float2bfloat16(v0.w);
        tmp[4] = __float2bfloat16(v1.x); tmp[5] = __float2bfloat16(v1.y);
        tmp[6] = __float2bfloat16(v1.z); tmp[7] = __float2bfloat16(v1.w);
        *reinterpret_cast<uint4*>(xb + idx) = *reinterpret_cast<const uint4*>(tmp);
    }
}

// ---------------------------------------------------------------------------
// Kernel 3: 128x256 tile, BK=32, 16x16x32 MFMA, 2 BLOCKS/CU (cross-block TLP
// is the overlap mechanism — one block's MFMA covers the other's barrier and
// staging stalls, m114). 512 threads = 8 waves (2M x 4N); per-wave 64x64 ->
// acc = 16 f32x4 = 64 AGPR; total per-thread ~110 regs -> fits 4 waves/SIMD.
//
// LDS: 3 bufs x {A 8KB, B 16KB} = 72 KB -> 2 blocks/CU (144 KB). Stage tile
// t+2 into buf (t+2)%3 during tile t (3 gloads/thread); counted vmcnt(3) at
// tile end (t+1 landed, issued a full tile earlier). Single barrier per
// K-tile, no sched pins (R11/R13: pins don't pay).
//
// Swizzle: involution swz(p)=p^((p>>3)&7) on 16B chunks per slot (R2 map,
// measured 0 conflicts; each wave read bijects onto one 1KB block). The XOR
// mask ((rsel>>1)&7)<<4 is independent of fragment index -> all read offsets
// are offX0 + i*1024 (2 live address regs).
// ---------------------------------------------------------------------------

__device__ __forceinline__ void gload16(const __hip_bfloat16* g, char* l) {
    __builtin_amdgcn_global_load_lds((const __attribute__((address_space(1))) void*)g,
                                     (__attribute__((address_space(3))) void*)l,
                                     16, 0, 0);
}

#define RD(off) (*(const bf16x8*)(smemc + (off)))

#define MFMA16 do {                                                                 \
    acc[0][0] = __builtin_amdgcn_mfma_f32_16x16x32_bf16(af0, bf0, acc[0][0],0,0,0); \
    acc[1][0] = __builtin_amdgcn_mfma_f32_16x16x32_bf16(af1, bf0, acc[1][0],0,0,0); \
    acc[2][0] = __builtin_amdgcn_mfma_f32_16x16x32_bf16(af2, bf0, acc[2][0],0,0,0); \
    acc[3][0] = __builtin_amdgcn_mfma_f32_16x16x32_bf16(af3, bf0, acc[3][0],0,0,0); \
    acc[0][1] = __builtin_amdgcn_mfma_f32_16x16x32_bf16(af0, bf1, acc[0][1],0,0,0); \
    acc[1][1] = __builtin_amdgcn_mfma_f32_16x16x32_bf16(af1, bf1, acc[1][1],0,0,0); \
    acc[2][1] = __builtin_amdgcn_mfma_f32_16x16x32_bf16(af2, bf1, acc[2][1],0,0,0); \
    acc[3][1] = __builtin_amdgcn_mfma_f32_16x16x32_bf16(af3, bf1, acc[3][1],0,0,0); \
    acc[0][2] = __builtin_amdgcn_mfma_f32_16x16x32_bf16(af0, bf2, acc[0][2],0,0,0); \
    acc[1][2] = __builtin_amdgcn_mfma_f32_16x16x32_bf16(af1, bf2, acc[1][2],0,0,0); \
    acc[2][2] = __builtin_amdgcn_mfma_f32_16x16x32_bf16(af2, bf2, acc[2][2],0,0,0); \
    acc[3][2] = __builtin_amdgcn_mfma_f32_16x16x32_bf16(af3, bf2, acc[3][2],0,0,0); \
    acc[0][3] = __builtin_amdgcn_mfma_f32_16x16x32_bf16(af0, bf3, acc[0][3],0,0,0); \
    acc[1][3] = __builtin_amdgcn_mfma_f32_16x16x32_bf16(af1, bf3, acc[1][3],0,0,0); \
    acc[2][3] = __builtin_amdgcn_mfma_f32_16x16x32_bf16(af2, bf3, acc[2][3],0,0,0); \
    acc[3][3] = __builtin_amdgcn_mfma_f32_16x16x32_bf16(af3, bf3, acc[3][3],0,0,0); \
} while (0)

#define W3 asm volatile("s_waitcnt vmcnt(3)" ::: "memory")
#define W0 asm volatile("s_waitcnt vmcnt(0)" ::: "memory")

// One K-tile: 8 ds_reads, optional 3-gload stage of t+2, 16 MFMA, fence, barrier.
#define KT(t, BC, BS, SG, WT) do {                                              \
    af0 = RD((BC)*24576 + offA0);                                               \
    af1 = RD((BC)*24576 + offA0 + 1024);                                        \
    af2 = RD((BC)*24576 + offA0 + 2048);                                        \
    af3 = RD((BC)*24576 + offA0 + 3072);                                        \
    bf0 = RD((BC)*24576 + 8192 + offB0);                                        \
    bf1 = RD((BC)*24576 + 8192 + offB0 + 1024);                                 \
    bf2 = RD((BC)*24576 + 8192 + offB0 + 2048);                                 \
    bf3 = RD((BC)*24576 + 8192 + offB0 + 3072);                                 \
    if (SG) {                                                                   \
        gload16(Abase + ((t)+2)*32 + gA,  smemc + (BS)*24576 + lA);             \
        gload16(Bbase + ((t)+2)*32 + gB0, smemc + (BS)*24576 + 8192 + lB0);     \
        gload16(Bbase + ((t)+2)*32 + gB1, smemc + (BS)*24576 + 8192 + lB1);     \
    }                                                                           \
    __builtin_amdgcn_s_setprio(1);                                              \
    MFMA16;                                                                     \
    __builtin_amdgcn_s_setprio(0);                                              \
    WT;                                                                         \
    __builtin_amdgcn_s_barrier();                                               \
} while (0)

#define KT_LAST(BC) do {                                                        \
    af0 = RD((BC)*24576 + offA0);                                               \
    af1 = RD((BC)*24576 + offA0 + 1024);                                        \
    af2 = RD((BC)*24576 + offA0 + 2048);                                        \
    af3 = RD((BC)*24576 + offA0 + 3072);                                        \
    bf0 = RD((BC)*24576 + 8192 + offB0);                                        \
    bf1 = RD((BC)*24576 + 8192 + offB0 + 1024);                                 \
    bf2 = RD((BC)*24576 + 8192 + offB0 + 2048);                                 \
    bf3 = RD((BC)*24576 + 8192 + offB0 + 3072);                                 \
    __builtin_amdgcn_s_setprio(1);                                              \
    MFMA16;                                                                     \
    __builtin_amdgcn_s_setprio(0);                                              \
} while (0)

__global__ __launch_bounds__(512, 4) void gemm10_kernel(const __hip_bfloat16* __restrict__ A,
                                                        const __hip_bfloat16* __restrict__ Wb,
                                                        const float* __restrict__ bias,
                                                        float* __restrict__ C) {
    __shared__ __align__(16) char smem_raw[3 * 24576];   // 72 KiB -> 2 blocks/CU
    char* smemc = smem_raw;

    const int tid  = threadIdx.x;
    const int lane = tid & 63;
    const int wid  = tid >> 6;        // 0..7
    const int wr   = wid >> 2;        // 0..1  (M half, 64 rows each)
    const int wc   = wid & 3;         // 0..3  (N quarter, 64 cols each)

    // T1: XCD-aware swizzle (nwg=1024, 1024%8==0 -> bijective). bn = XCD id.
    const int bid = blockIdx.x;
    const int swz = (bid & 7) * 128 + (bid >> 3);
    const int bn  = swz >> 7;         // 0..7
    const int bm  = swz & 127;        // 0..127

    const __hip_bfloat16* Abase = A  + (size_t)bm * 128 * KDIM;
    const __hip_bfloat16* Bbase = Wb + (size_t)bn * 256 * KDIM;

    // --- staging source offsets (inverse involution, linear LDS dest) ---
    // A slot: 512 chunks, thread covers chunk tid.
    // B slot: 1024 chunks, thread covers chunks tid and tid+512.
    int gA, gB0, gB1;
    {
        const int cA = tid;
        const int sA = cA ^ ((cA >> 3) & 7);
        gA = (sA >> 2) * KDIM + (sA & 3) * 8;       // bf16 elements
        const int c0 = tid;
        const int s0 = c0 ^ ((c0 >> 3) & 7);
        gB0 = (s0 >> 2) * KDIM + (s0 & 3) * 8;
        const int c1 = tid + 512;
        const int s1 = c1 ^ ((c1 >> 3) & 7);
        gB1 = (s1 >> 2) * KDIM + (s1 & 3) * 8;
    }
    const int lA  = wid * 1024;            // bytes (wave-uniform dest bases)
    const int lB0 = wid * 1024;
    const int lB1 = 8192 + wid * 1024;

    // --- fragment read offsets: XOR mask depends only on rsel ->
    //     offX(i) = offX0 + i*1024 ---
    const int rsel = lane & 15;
    const int kq   = lane >> 4;            // 0..3
    const int xmask = ((rsel >> 1) & 7) << 4;
    const int offA0 = (((wr * 64 + rsel) * 64) + kq * 16) ^ xmask;   // A slot bytes
    const int offB0 = (((wc * 64 + rsel) * 64) + kq * 16) ^ xmask;   // B slot bytes

    f32x4 acc[4][4];
#pragma unroll
    for (int m = 0; m < 4; ++m)
#pragma unroll
        for (int n = 0; n < 4; ++n)
            acc[m][n] = (f32x4){0.f, 0.f, 0.f, 0.f};

    bf16x8 af0, af1, af2, af3, bf0, bf1, bf2, bf3;

    // --- prologue: stage t0 -> buf0, t1 -> buf1 (6 gloads/thread) ---
    gload16(Abase +  0 + gA,  smemc + lA);
    gload16(Bbase +  0 + gB0, smemc + 8192 + lB0);
    gload16(Bbase +  0 + gB1, smemc + 8192 + lB1);
    gload16(Abase + 32 + gA,  smemc + 24576 + lA);
    gload16(Bbase + 32 + gB0, smemc + 24576 + 8192 + lB0);
    gload16(Bbase + 32 + gB1, smemc + 24576 + 8192 + lB1);
    W3;                       // t0 landed; t1's 3 may stay in flight
    __builtin_amdgcn_s_barrier();

    // --- main loop: KDIM/32 = 64 K-tiles, buf = t%3, stage t+2 -> (t+2)%3 ---
    for (int t = 0; t < 60; t += 3) {
        KT(t,     0, 2, 1, W3);
        KT(t + 1, 1, 0, 1, W3);
        KT(t + 2, 2, 1, 1, W3);
    }
    KT(60, 0, 2, 1, W3);      // stages t62
    KT(61, 1, 0, 1, W3);      // stages t63
    KT(62, 2, 1, 0, W0);      // drain: t63 landed
    KT_LAST(0);               // t63 (63%3 == 0)

    // --- epilogue: C/D layout col = lane&15, row = (lane>>4)*4 + r ---
    const int r0 = kq * 4;
#pragma unroll
    for (int n = 0; n < 4; ++n) {
        const int cg = bn * 256 + wc * 64 + n * 16 + rsel;
        const float bv = bias[cg];
#pragma unroll
        for (int m = 0; m < 4; ++m) {
            const size_t rg = (size_t)bm * 128 + wr * 64 + m * 16 + r0;
#pragma unroll
            for (int r = 0; r < 4; ++r)
                C[(rg + r) * NDIM + cg] = acc[m][n][r] + bv;
        }
    }
}

// ---------------------------------------------------------------------------
// Fallback: naive fused fp32 GEMM (only if workspace too small).
// ---------------------------------------------------------------------------
__global__ void naive_kernel(const float* __restrict__ x,
                             const float* __restrict__ leaf,
                             const float* __restrict__ W,
                             const float* __restrict__ bias,
                             float* __restrict__ out) {
    long idx = (long)blockIdx.x * blockDim.x + threadIdx.x;
    if (idx >= (long)MROWS * NDIM) return;
    int  o = (int)(idx % NDIM);
    long m = idx / NDIM;
    int o2 = o / 169, o1 = (o / 13) % 13, o0 = o % 13;
    float acc = 0.f;
    for (int i = 0; i < KDIM; ++i) {
        int i2 = i / 169, i1 = (i / 13) % 13, i0 = i % 13;
        float d = 0.f;
#pragma unroll
        for (int r = 0; r < RANKD; ++r)
            d += leaf[( r     * LEAFD + o2) * LEAFD + i2]
               * leaf[((4 + r) * LEAFD + o1) * LEAFD + i1]
               * leaf[((8 + r) * LEAFD + o0) * LEAFD + i0];
        acc += x[m * KDIM + i] * (W[(long)o * KDIM + i] + d);
    }
    out[idx] = acc + bias[o];
}

// ---------------------------------------------------------------------------
extern "C" void kernel_launch(void* const* d_in, const int* in_sizes, int n_in,
                              void* d_out, int out_size, void* d_ws, size_t ws_size,
                              hipStream_t stream) {
    const float* x      = (const float*)d_in[0];
    const float* leaf   = (const float*)d_in[1];
    const float* weight = (const float*)d_in[2];
    const float* bias   = (const float*)d_in[3];
    float* out = (float*)d_out;

    const size_t needA = (size_t)MROWS * KDIM * sizeof(__hip_bfloat16);  // 64 MiB
    const size_t needW = (size_t)NDIM  * KDIM * sizeof(__hip_bfloat16);  // 8 MiB

    if (ws_size >= needA + needW) {
        __hip_bfloat16* xb = (__hip_bfloat16*)d_ws;
        __hip_bfloat16* wb = (__hip_bfloat16*)((char*)d_ws + needA);
        build_w_kernel<<<(NDIM * KDIM + 255) / 256, 256, 0, stream>>>(weight, leaf, wb);
        cvt_kernel<<<2048, 256, 0, stream>>>(x, xb, MROWS * KDIM);
        gemm10_kernel<<<(MROWS / 128) * (NDIM / 256), 512, 0, stream>>>(xb, wb, bias, out);
    } else {
        long total = (long)MROWS * NDIM;
        naive_kernel<<<(int)((total + 255) / 256), 256, 0, stream>>>(x, leaf, weight, bias, out);
    }
}

// Round 15
// 209.560 us; speedup vs baseline: 1.0431x; 1.0431x over previous
//
#include <hip/hip_runtime.h>
#include <hip/hip_bf16.h>
#include <stdint.h>

#define MROWS 16384   // B*S
#define KDIM  2048
#define NDIM  2048
#define LEAFD 13
#define RANKD 4

typedef __bf16 bf16x8 __attribute__((ext_vector_type(8)));
typedef float  f32x4  __attribute__((ext_vector_type(4)));

// ---------------------------------------------------------------------------
// Kernel 1: w_bf[o,i] = bf16( weight[o,i] + sum_r L0[r,o2,i2]*L1[r,o1,i1]*L2[r,o0,i0] )
// ---------------------------------------------------------------------------
__global__ void build_w_kernel(const float* __restrict__ weight,
                               const float* __restrict__ leaf,
                               __hip_bfloat16* __restrict__ wbf) {
    __shared__ float ll[3 * RANKD * LEAFD * LEAFD];
    for (int t = threadIdx.x; t < 3 * RANKD * LEAFD * LEAFD; t += blockDim.x)
        ll[t] = leaf[t];
    __syncthreads();
    int idx = blockIdx.x * blockDim.x + threadIdx.x;
    if (idx >= NDIM * KDIM) return;
    int o = idx / KDIM, i = idx % KDIM;
    int o2 = o / 169, o1 = (o / 13) % 13, o0 = o % 13;
    int i2 = i / 169, i1 = (i / 13) % 13, i0 = i % 13;
    float d = 0.f;
#pragma unroll
    for (int r = 0; r < RANKD; ++r) {
        float a = ll[( r            * LEAFD + o2) * LEAFD + i2];
        float b = ll[((RANKD   + r) * LEAFD + o1) * LEAFD + i1];
        float c = ll[((2*RANKD + r) * LEAFD + o0) * LEAFD + i0];
        d += a * b * c;
    }
    wbf[idx] = __float2bfloat16(weight[idx] + d);
}

// ---------------------------------------------------------------------------
// Kernel 2: fp32 -> bf16 conversion of activations (8 floats/thread)
// ---------------------------------------------------------------------------
__global__ void cvt_kernel(const float* __restrict__ x,
                           __hip_bfloat16* __restrict__ xb, int n) {
    long stride = (long)gridDim.x * blockDim.x * 8;
    for (long idx = ((long)blockIdx.x * blockDim.x + threadIdx.x) * 8; idx < n; idx += stride) {
        float4 v0 = *reinterpret_cast<const float4*>(x + idx);
        float4 v1 = *reinterpret_cast<const float4*>(x + idx + 4);
        __hip_bfloat16 tmp[8];
        tmp[0] = __float2bfloat16(v0.x); tmp[1] = __float2bfloat16(v0.y);
        tmp[2] = __float2bfloat16(v0.z); tmp[3] = __float2bfloat16(v0.w);
        tmp[4] = __float2bfloat16(v1.x); tmp[5] = __float2bfloat16(v1.y);
        tmp[6] = __float2bfloat16(v1.z); tmp[7] = __float2bfloat16(v1.w);
        *reinterpret_cast<uint4*>(xb + idx) = *reinterpret_cast<const uint4*>(tmp);
    }
}

// ---------------------------------------------------------------------------
// Kernel 3: R2's verified 256x256/BK=64 8-phase K-loop, made PERSISTENT over
// two M-adjacent output tiles (2q, 2q+1) x same bn per block. 256 blocks,
// one continuous 64-K-tile staging cadence that wraps across the tile
// boundary: t=30/31 prefetch tile-2's first K-tiles, epilogue-1 runs while
// they are in flight, no second prologue, no round transition.
// Per-XCD: all 32 blocks share one bn -> 1 MB B panel L2-resident for the
// whole kernel. K-loop body, swizzles, vmcnt cadence identical to R2
// (140.4 us, 0 bank conflicts, measured best of 11 structures).
// ---------------------------------------------------------------------------

__device__ __forceinline__ void gload16(const __hip_bfloat16* g, char* l) {
    __builtin_amdgcn_global_load_lds((const __attribute__((address_space(1))) void*)g,
                                     (__attribute__((address_space(3))) void*)l,
                                     16, 0, 0);
}

#define STAGE(base, kb, bufi, slot) do {                                          \
    gload16((base) + (kb) + gOff0, smemc + (bufi)*65536 + (slot)*16384 + lOff0);  \
    gload16((base) + (kb) + gOff1, smemc + (bufi)*65536 + (slot)*16384 + lOff1);  \
} while (0)

#define LOAD_A(mh, kk, bufc)                                                        \
    af0 = *(const bf16x8*)(smemc + (bufc)*65536 + (kk)*32768 + offA[(mh)*4+0]);     \
    af1 = *(const bf16x8*)(smemc + (bufc)*65536 + (kk)*32768 + offA[(mh)*4+1]);     \
    af2 = *(const bf16x8*)(smemc + (bufc)*65536 + (kk)*32768 + offA[(mh)*4+2]);     \
    af3 = *(const bf16x8*)(smemc + (bufc)*65536 + (kk)*32768 + offA[(mh)*4+3]);

#define LOAD_B(kk, bufc)                                                                    \
    bf0 = *(const bf16x8*)(smemc + (bufc)*65536 + (kk)*32768 + 16384 + offB[0]);            \
    bf1 = *(const bf16x8*)(smemc + (bufc)*65536 + (kk)*32768 + 16384 + offB[1]);            \
    bf2 = *(const bf16x8*)(smemc + (bufc)*65536 + (kk)*32768 + 16384 + offB[2]);            \
    bf3 = *(const bf16x8*)(smemc + (bufc)*65536 + (kk)*32768 + 16384 + offB[3]);

#define MFMA_Q(mh) do {                                                                   \
    acc[(mh)*4+0][0] = __builtin_amdgcn_mfma_f32_16x16x32_bf16(af0, bf0, acc[(mh)*4+0][0], 0,0,0); \
    acc[(mh)*4+1][0] = __builtin_amdgcn_mfma_f32_16x16x32_bf16(af1, bf0, acc[(mh)*4+1][0], 0,0,0); \
    acc[(mh)*4+2][0] = __builtin_amdgcn_mfma_f32_16x16x32_bf16(af2, bf0, acc[(mh)*4+2][0], 0,0,0); \
    acc[(mh)*4+3][0] = __builtin_amdgcn_mfma_f32_16x16x32_bf16(af3, bf0, acc[(mh)*4+3][0], 0,0,0); \
    acc[(mh)*4+0][1] = __builtin_amdgcn_mfma_f32_16x16x32_bf16(af0, bf1, acc[(mh)*4+0][1], 0,0,0); \
    acc[(mh)*4+1][1] = __builtin_amdgcn_mfma_f32_16x16x32_bf16(af1, bf1, acc[(mh)*4+1][1], 0,0,0); \
    acc[(mh)*4+2][1] = __builtin_amdgcn_mfma_f32_16x16x32_bf16(af2, bf1, acc[(mh)*4+2][1], 0,0,0); \
    acc[(mh)*4+3][1] = __builtin_amdgcn_mfma_f32_16x16x32_bf16(af3, bf1, acc[(mh)*4+3][1], 0,0,0); \
    acc[(mh)*4+0][2] = __builtin_amdgcn_mfma_f32_16x16x32_bf16(af0, bf2, acc[(mh)*4+0][2], 0,0,0); \
    acc[(mh)*4+1][2] = __builtin_amdgcn_mfma_f32_16x16x32_bf16(af1, bf2, acc[(mh)*4+1][2], 0,0,0); \
    acc[(mh)*4+2][2] = __builtin_amdgcn_mfma_f32_16x16x32_bf16(af2, bf2, acc[(mh)*4+2][2], 0,0,0); \
    acc[(mh)*4+3][2] = __builtin_amdgcn_mfma_f32_16x16x32_bf16(af3, bf2, acc[(mh)*4+3][2], 0,0,0); \
    acc[(mh)*4+0][3] = __builtin_amdgcn_mfma_f32_16x16x32_bf16(af0, bf3, acc[(mh)*4+0][3], 0,0,0); \
    acc[(mh)*4+1][3] = __builtin_amdgcn_mfma_f32_16x16x32_bf16(af1, bf3, acc[(mh)*4+1][3], 0,0,0); \
    acc[(mh)*4+2][3] = __builtin_amdgcn_mfma_f32_16x16x32_bf16(af2, bf3, acc[(mh)*4+2][3], 0,0,0); \
    acc[(mh)*4+3][3] = __builtin_amdgcn_mfma_f32_16x16x32_bf16(af3, bf3, acc[(mh)*4+3][3], 0,0,0); \
} while (0)

#define BARRIER_IN do {                                     \
    __builtin_amdgcn_sched_barrier(0);                      \
    __builtin_amdgcn_s_barrier();                           \
    asm volatile("s_waitcnt lgkmcnt(0)" ::: "memory");      \
    __builtin_amdgcn_sched_barrier(0);                      \
    __builtin_amdgcn_s_setprio(1);                          \
} while (0)

#define BARRIER_OUT do {                                    \
    __builtin_amdgcn_s_setprio(0);                          \
    __builtin_amdgcn_sched_barrier(0);                      \
    __builtin_amdgcn_s_barrier();                           \
    __builtin_amdgcn_sched_barrier(0);                      \
} while (0)

#define WAIT4 asm volatile("s_waitcnt vmcnt(4)" ::: "memory")
#define WAIT0 asm volatile("s_waitcnt vmcnt(0)" ::: "memory")
#define WNONE do {} while (0)

// R2's KTILE with explicit stage bases/offsets so the cadence can wrap
// across the M-tile boundary. K1 = k-elem offset of k-tile t+1 (mod 32),
// K2 = of t+2; AP1/AP2 = A panel base for those tiles.
#define KTILEM(BC, AP1, K1, AP2, K2, S0, S1, S2, S3, W3) do {       \
    /* p0 */                                                        \
    LOAD_B(0, BC); LOAD_A(0, 0, BC);                                \
    if (S0) STAGE(AP1, (K1)+32, (BC)^1, 2);                         \
    BARRIER_IN; MFMA_Q(0); BARRIER_OUT;                             \
    /* p1 */                                                        \
    LOAD_A(1, 0, BC);                                               \
    if (S1) STAGE(Bbase, (K1)+32, (BC)^1, 3);                       \
    BARRIER_IN; MFMA_Q(1); BARRIER_OUT;                             \
    /* p2 */                                                        \
    LOAD_B(1, BC); LOAD_A(0, 1, BC);                                \
    if (S2) STAGE(AP2, (K2), (BC), 0);                              \
    BARRIER_IN; MFMA_Q(0); BARRIER_OUT;                             \
    /* p3 */                                                        \
    LOAD_A(1, 1, BC);                                               \
    if (S3) STAGE(Bbase, (K2), (BC), 1);                            \
    W3;                                                             \
    BARRIER_IN; MFMA_Q(1); BARRIER_OUT;                             \
} while (0)

#define EPILOG(ROWBASE) do {                                                    \
    _Pragma("unroll")                                                           \
    for (int n = 0; n < 4; ++n) {                                               \
        const int cg = bn * 256 + wc * 64 + n * 16 + col0;                      \
        const float bv = bias[cg];                                              \
        _Pragma("unroll")                                                       \
        for (int m = 0; m < 8; ++m) {                                           \
            const size_t rg = (size_t)(ROWBASE) + wr * 128 + m * 16 + r0;       \
            _Pragma("unroll")                                                   \
            for (int r = 0; r < 4; ++r)                                         \
                C[(rg + r) * NDIM + cg] = acc[m][n][r] + bv;                    \
        }                                                                       \
    }                                                                           \
} while (0)

__global__ __launch_bounds__(512, 2) void gemm11_kernel(const __hip_bfloat16* __restrict__ A,
                                                        const __hip_bfloat16* __restrict__ Wb,
                                                        const float* __restrict__ bias,
                                                        float* __restrict__ C) {
    __shared__ __align__(16) __hip_bfloat16 smem[2][4][8192];  // 128 KiB
    char* smemc = (char*)smem;

    const int tid  = threadIdx.x;
    const int lane = tid & 63;
    const int wid  = tid >> 6;        // 0..7
    const int wr   = wid >> 2;        // 0..1  (M half)
    const int wc   = wid & 3;         // 0..3  (N quarter)

    // 256 blocks: swz = (bid&7)*32 + bid>>3; bn = swz>>5 (== XCD id),
    // q = swz&31 -> M-tile pair (2q, 2q+1). Each XCD's 32 blocks share bn.
    const int bid = blockIdx.x;
    const int swz = (bid & 7) * 32 + (bid >> 3);
    const int bn  = swz >> 5;         // 0..7
    const int q   = swz & 31;         // 0..31

    const __hip_bfloat16* Abase0 = A + (size_t)(q * 2) * 256 * KDIM;
    const __hip_bfloat16* Abase1 = Abase0 + (size_t)256 * KDIM;
    const __hip_bfloat16* Bbase  = Wb + (size_t)bn * 256 * KDIM;

    // --- staging source offsets (inverse-swizzled global, linear LDS dest) ---
    const int c0  = wid * 64 + lane;          // chunk 0..511
    const int c1  = 512 + c0;                 // chunk 512..1023
    const int cs0 = c0 ^ ((c0 >> 3) & 7);
    const int cs1 = c1 ^ ((c1 >> 3) & 7);
    const int gOff0 = (cs0 >> 2) * KDIM + (cs0 & 3) * 8;   // elements
    const int gOff1 = (cs1 >> 2) * KDIM + (cs1 & 3) * 8;
    const int lOff0 = wid * 1024;                          // bytes (wave-uniform)
    const int lOff1 = 8192 + wid * 1024;

    // --- swizzled ds_read byte offsets within a 16 KB slot (R2 map, 0-conflict) ---
    const int rsel = lane & 15;
    const int kby  = (lane >> 4) * 16;
    int offA[8], offB[4];
#pragma unroll
    for (int m = 0; m < 8; ++m) {
        int a = (wr * 128 + m * 16 + rsel) * 64 + kby;
        offA[m] = a ^ (((a >> 7) & 7) << 4);
    }
#pragma unroll
    for (int n = 0; n < 4; ++n) {
        int a = (wc * 64 + n * 16 + rsel) * 64 + kby;
        offB[n] = a ^ (((a >> 7) & 7) << 4);
    }

    f32x4 acc[8][4];
#pragma unroll
    for (int m = 0; m < 8; ++m)
#pragma unroll
        for (int n = 0; n < 4; ++n)
            acc[m][n] = (f32x4){0.f, 0.f, 0.f, 0.f};

    bf16x8 af0, af1, af2, af3, bf0, bf1, bf2, bf3;

    const int col0 = lane & 15;
    const int r0   = (lane >> 4) * 4;

    // --- prologue: stage 6 half-tiles (t0 all 4 slots + t1 slots 0,1) ---
    STAGE(Abase0,  0, 0, 0);
    STAGE(Bbase,   0, 0, 1);
    STAGE(Abase0, 32, 0, 2);
    STAGE(Bbase,  32, 0, 3);
    STAGE(Abase0, 64, 1, 0);
    STAGE(Bbase,  64, 1, 1);
    WAIT4;                    // tile0 fully landed
    __builtin_amdgcn_sched_barrier(0);
    __builtin_amdgcn_s_barrier();
    __builtin_amdgcn_sched_barrier(0);

    // --- first M-tile: K-tiles 0..31 (stage cadence wraps into tile 2) ---
    for (int t = 0; t < 30; t += 2) {
        KTILEM(0, Abase0, (t+1)*64, Abase0, (t+2)*64, 1, 1, 1, 1, WAIT4);
        KTILEM(1, Abase0, (t+2)*64, Abase0, (t+3)*64, 1, 1, 1, 1, WAIT4);
    }
    // t=30: stages A-khi(31)@A0, B-khi(31), A-klo(k0)@A1, B-klo(k0)
    KTILEM(0, Abase0, 31*64, Abase1, 0, 1, 1, 1, 1, WAIT4);
    // t=31: stages A-khi(k0)@A1, B-khi(k0), A-klo(k1)@A1, B-klo(k1)
    KTILEM(1, Abase1, 0, Abase1, 64, 1, 1, 1, 1, WAIT4);

    // --- epilogue 1 (rows of tile 2q); prefetched loads land meanwhile ---
    EPILOG((size_t)(q * 2) * 256);
#pragma unroll
    for (int m = 0; m < 8; ++m)
#pragma unroll
        for (int n = 0; n < 4; ++n)
            acc[m][n] = (f32x4){0.f, 0.f, 0.f, 0.f};

    // --- second M-tile: K-tiles 32..63 (buf parity continues: 32 -> buf0) ---
    for (int t = 32; t < 62; t += 2) {
        KTILEM(0, Abase1, (t-31)*64, Abase1, (t-30)*64, 1, 1, 1, 1, WAIT4);
        KTILEM(1, Abase1, (t-30)*64, Abase1, (t-29)*64, 1, 1, 1, 1, WAIT4);
    }
    KTILEM(0, Abase1, 31*64, Abase1, 0, 1, 1, 0, 0, WAIT0);   // stages khi(63); drain
    KTILEM(1, Abase1, 0, Abase1, 0, 0, 0, 0, 0, WNONE);       // k-tile 63

    // --- epilogue 2 (rows of tile 2q+1) ---
    EPILOG((size_t)(q * 2 + 1) * 256);
}

// ---------------------------------------------------------------------------
// Fallback: naive fused fp32 GEMM (only if workspace too small).
// ---------------------------------------------------------------------------
__global__ void naive_kernel(const float* __restrict__ x,
                             const float* __restrict__ leaf,
                             const float* __restrict__ W,
                             const float* __restrict__ bias,
                             float* __restrict__ out) {
    long idx = (long)blockIdx.x * blockDim.x + threadIdx.x;
    if (idx >= (long)MROWS * NDIM) return;
    int  o = (int)(idx % NDIM);
    long m = idx / NDIM;
    int o2 = o / 169, o1 = (o / 13) % 13, o0 = o % 13;
    float acc = 0.f;
    for (int i = 0; i < KDIM; ++i) {
        int i2 = i / 169, i1 = (i / 13) % 13, i0 = i % 13;
        float d = 0.f;
#pragma unroll
        for (int r = 0; r < RANKD; ++r)
            d += leaf[( r     * LEAFD + o2) * LEAFD + i2]
               * leaf[((4 + r) * LEAFD + o1) * LEAFD + i1]
               * leaf[((8 + r) * LEAFD + o0) * LEAFD + i0];
        acc += x[m * KDIM + i] * (W[(long)o * KDIM + i] + d);
    }
    out[idx] = acc + bias[o];
}

// ---------------------------------------------------------------------------
extern "C" void kernel_launch(void* const* d_in, const int* in_sizes, int n_in,
                              void* d_out, int out_size, void* d_ws, size_t ws_size,
                              hipStream_t stream) {
    const float* x      = (const float*)d_in[0];
    const float* leaf   = (const float*)d_in[1];
    const float* weight = (const float*)d_in[2];
    const float* bias   = (const float*)d_in[3];
    float* out = (float*)d_out;

    const size_t needA = (size_t)MROWS * KDIM * sizeof(__hip_bfloat16);  // 64 MiB
    const size_t needW = (size_t)NDIM  * KDIM * sizeof(__hip_bfloat16);  // 8 MiB

    if (ws_size >= needA + needW) {
        __hip_bfloat16* xb = (__hip_bfloat16*)d_ws;
        __hip_bfloat16* wb = (__hip_bfloat16*)((char*)d_ws + needA);
        build_w_kernel<<<(NDIM * KDIM + 255) / 256, 256, 0, stream>>>(weight, leaf, wb);
        cvt_kernel<<<2048, 256, 0, stream>>>(x, xb, MROWS * KDIM);
        gemm11_kernel<<<256, 512, 0, stream>>>(xb, wb, bias, out);
    } else {
        long total = (long)MROWS * NDIM;
        naive_kernel<<<(int)((total + 255) / 256), 256, 0, stream>>>(x, leaf, weight, bias, out);
    }
}

// Round 16
// 207.643 us; speedup vs baseline: 1.0528x; 1.0092x over previous
//
#include <hip/hip_runtime.h>
#include <hip/hip_bf16.h>
#include <stdint.h>

#define MROWS 16384   // B*S
#define KDIM  2048
#define NDIM  2048
#define LEAFD 13
#define RANKD 4

typedef __bf16 bf16x8 __attribute__((ext_vector_type(8)));
typedef float  f32x4  __attribute__((ext_vector_type(4)));

// ---------------------------------------------------------------------------
// Kernel 1 (merged prep): blocks [0,16384) build w_bf; blocks [16384,18432)
// convert x fp32->bf16 (grid-stride, 8 floats/thread). One launch, one gap.
// ---------------------------------------------------------------------------
__global__ void prep_kernel(const float* __restrict__ x,
                            const float* __restrict__ leaf,
                            const float* __restrict__ weight,
                            __hip_bfloat16* __restrict__ xb,
                            __hip_bfloat16* __restrict__ wbf) {
    const int bid = blockIdx.x;
    if (bid < 16384) {
        __shared__ float ll[3 * RANKD * LEAFD * LEAFD];
        for (int t = threadIdx.x; t < 3 * RANKD * LEAFD * LEAFD; t += blockDim.x)
            ll[t] = leaf[t];
        __syncthreads();
        int idx = bid * 256 + threadIdx.x;
        int o = idx / KDIM, i = idx % KDIM;
        int o2 = o / 169, o1 = (o / 13) % 13, o0 = o % 13;
        int i2 = i / 169, i1 = (i / 13) % 13, i0 = i % 13;
        float d = 0.f;
#pragma unroll
        for (int r = 0; r < RANKD; ++r) {
            float a = ll[( r            * LEAFD + o2) * LEAFD + i2];
            float b = ll[((RANKD   + r) * LEAFD + o1) * LEAFD + i1];
            float c = ll[((2*RANKD + r) * LEAFD + o0) * LEAFD + i0];
            d += a * b * c;
        }
        wbf[idx] = __float2bfloat16(weight[idx] + d);
    } else {
        const long n = (long)MROWS * KDIM;
        const long stride = (long)2048 * 256 * 8;
        for (long idx = ((long)(bid - 16384) * 256 + threadIdx.x) * 8; idx < n; idx += stride) {
            float4 v0 = *reinterpret_cast<const float4*>(x + idx);
            float4 v1 = *reinterpret_cast<const float4*>(x + idx + 4);
            __hip_bfloat16 tmp[8];
            tmp[0] = __float2bfloat16(v0.x); tmp[1] = __float2bfloat16(v0.y);
            tmp[2] = __float2bfloat16(v0.z); tmp[3] = __float2bfloat16(v0.w);
            tmp[4] = __float2bfloat16(v1.x); tmp[5] = __float2bfloat16(v1.y);
            tmp[6] = __float2bfloat16(v1.z); tmp[7] = __float2bfloat16(v1.w);
            *reinterpret_cast<uint4*>(xb + idx) = *reinterpret_cast<const uint4*>(tmp);
        }
    }
}

// ---------------------------------------------------------------------------
// Kernel 2: 256x256 tile, BK=64, 16x16x32 MFMA, ONE barrier + ONE vmcnt(0)
// fence per 64-K tile (32 total), no internal pins. R2's measured-0-conflict
// LDS maps and staging verbatim; 8 live frags max (VGPR ~120, +128 AGPR
// acc = 248 <= 256 -> 2 waves/SIMD preserved).
// LDS: 2 bufs x 64KB {A-klo, B-klo, A-khi, B-khi} x 16KB. Stage t+1 (8
// gloads) at span start of t into buf^1 (freed by t-1's end barrier);
// vmcnt(0) at span end is ~4000 cyc after issue -> latency fully hidden.
// ---------------------------------------------------------------------------

__device__ __forceinline__ void gload16(const __hip_bfloat16* g, char* l) {
    __builtin_amdgcn_global_load_lds((const __attribute__((address_space(1))) void*)g,
                                     (__attribute__((address_space(3))) void*)l,
                                     16, 0, 0);
}

#define STAGE(base, kb, bufi, slot) do {                                          \
    gload16((base) + (kb) + gOff0, smemc + (bufi)*65536 + (slot)*16384 + lOff0);  \
    gload16((base) + (kb) + gOff1, smemc + (bufi)*65536 + (slot)*16384 + lOff1);  \
} while (0)

#define LOAD_A(mh, kk, bufc)                                                        \
    af0 = *(const bf16x8*)(smemc + (bufc)*65536 + (kk)*32768 + offA[(mh)*4+0]);     \
    af1 = *(const bf16x8*)(smemc + (bufc)*65536 + (kk)*32768 + offA[(mh)*4+1]);     \
    af2 = *(const bf16x8*)(smemc + (bufc)*65536 + (kk)*32768 + offA[(mh)*4+2]);     \
    af3 = *(const bf16x8*)(smemc + (bufc)*65536 + (kk)*32768 + offA[(mh)*4+3]);

#define LOAD_B(kk, bufc)                                                                    \
    bf0 = *(const bf16x8*)(smemc + (bufc)*65536 + (kk)*32768 + 16384 + offB[0]);            \
    bf1 = *(const bf16x8*)(smemc + (bufc)*65536 + (kk)*32768 + 16384 + offB[1]);            \
    bf2 = *(const bf16x8*)(smemc + (bufc)*65536 + (kk)*32768 + 16384 + offB[2]);            \
    bf3 = *(const bf16x8*)(smemc + (bufc)*65536 + (kk)*32768 + 16384 + offB[3]);

#define MFMA_Q(mh) do {                                                                   \
    acc[(mh)*4+0][0] = __builtin_amdgcn_mfma_f32_16x16x32_bf16(af0, bf0, acc[(mh)*4+0][0], 0,0,0); \
    acc[(mh)*4+1][0] = __builtin_amdgcn_mfma_f32_16x16x32_bf16(af1, bf0, acc[(mh)*4+1][0], 0,0,0); \
    acc[(mh)*4+2][0] = __builtin_amdgcn_mfma_f32_16x16x32_bf16(af2, bf0, acc[(mh)*4+2][0], 0,0,0); \
    acc[(mh)*4+3][0] = __builtin_amdgcn_mfma_f32_16x16x32_bf16(af3, bf0, acc[(mh)*4+3][0], 0,0,0); \
    acc[(mh)*4+0][1] = __builtin_amdgcn_mfma_f32_16x16x32_bf16(af0, bf1, acc[(mh)*4+0][1], 0,0,0); \
    acc[(mh)*4+1][1] = __builtin_amdgcn_mfma_f32_16x16x32_bf16(af1, bf1, acc[(mh)*4+1][1], 0,0,0); \
    acc[(mh)*4+2][1] = __builtin_amdgcn_mfma_f32_16x16x32_bf16(af2, bf1, acc[(mh)*4+2][1], 0,0,0); \
    acc[(mh)*4+3][1] = __builtin_amdgcn_mfma_f32_16x16x32_bf16(af3, bf1, acc[(mh)*4+3][1], 0,0,0); \
    acc[(mh)*4+0][2] = __builtin_amdgcn_mfma_f32_16x16x32_bf16(af0, bf2, acc[(mh)*4+0][2], 0,0,0); \
    acc[(mh)*4+1][2] = __builtin_amdgcn_mfma_f32_16x16x32_bf16(af1, bf2, acc[(mh)*4+1][2], 0,0,0); \
    acc[(mh)*4+2][2] = __builtin_amdgcn_mfma_f32_16x16x32_bf16(af2, bf2, acc[(mh)*4+2][2], 0,0,0); \
    acc[(mh)*4+3][2] = __builtin_amdgcn_mfma_f32_16x16x32_bf16(af3, bf2, acc[(mh)*4+3][2], 0,0,0); \
    acc[(mh)*4+0][3] = __builtin_amdgcn_mfma_f32_16x16x32_bf16(af0, bf3, acc[(mh)*4+0][3], 0,0,0); \
    acc[(mh)*4+1][3] = __builtin_amdgcn_mfma_f32_16x16x32_bf16(af1, bf3, acc[(mh)*4+1][3], 0,0,0); \
    acc[(mh)*4+2][3] = __builtin_amdgcn_mfma_f32_16x16x32_bf16(af2, bf3, acc[(mh)*4+2][3], 0,0,0); \
    acc[(mh)*4+3][3] = __builtin_amdgcn_mfma_f32_16x16x32_bf16(af3, bf3, acc[(mh)*4+3][3], 0,0,0); \
} while (0)

#define W0 asm volatile("s_waitcnt vmcnt(0)" ::: "memory")
#define WN do {} while (0)

// One 64-K tile: stage t+1 (8 gloads), 24 ds_reads + 64 MFMA interleaved by
// the compiler (8 frags live max), one fence + one barrier.
#define SPAN(t, BC, SG, WT) do {                                    \
    if (SG) {                                                       \
        STAGE(Abase, ((t)+1)*64,      (BC)^1, 0);                   \
        STAGE(Bbase, ((t)+1)*64,      (BC)^1, 1);                   \
        STAGE(Abase, ((t)+1)*64 + 32, (BC)^1, 2);                   \
        STAGE(Bbase, ((t)+1)*64 + 32, (BC)^1, 3);                   \
    }                                                               \
    LOAD_B(0, BC); LOAD_A(0, 0, BC);                                \
    __builtin_amdgcn_s_setprio(1);                                  \
    MFMA_Q(0);                                                      \
    __builtin_amdgcn_s_setprio(0);                                  \
    LOAD_A(1, 0, BC);                                               \
    __builtin_amdgcn_s_setprio(1);                                  \
    MFMA_Q(1);                                                      \
    __builtin_amdgcn_s_setprio(0);                                  \
    LOAD_B(1, BC); LOAD_A(0, 1, BC);                                \
    __builtin_amdgcn_s_setprio(1);                                  \
    MFMA_Q(0);                                                      \
    __builtin_amdgcn_s_setprio(0);                                  \
    LOAD_A(1, 1, BC);                                               \
    __builtin_amdgcn_s_setprio(1);                                  \
    MFMA_Q(1);                                                      \
    __builtin_amdgcn_s_setprio(0);                                  \
    WT;                                                             \
    __builtin_amdgcn_s_barrier();                                   \
} while (0)

__global__ __launch_bounds__(512, 1) void gemm12_kernel(const __hip_bfloat16* __restrict__ A,
                                                        const __hip_bfloat16* __restrict__ Wb,
                                                        const float* __restrict__ bias,
                                                        float* __restrict__ C) {
    __shared__ __align__(16) __hip_bfloat16 smem[2][4][8192];  // 128 KiB
    char* smemc = (char*)smem;

    const int tid  = threadIdx.x;
    const int lane = tid & 63;
    const int wid  = tid >> 6;        // 0..7
    const int wr   = wid >> 2;        // 0..1  (M half)
    const int wc   = wid & 3;         // 0..3  (N quarter)

    // T1: XCD-aware swizzle (nwg=512, 512%8==0 -> bijective).
    const int bid = blockIdx.x;
    const int swz = (bid & 7) * 64 + (bid >> 3);
    const int bn  = swz >> 6;         // 0..7
    const int bm  = swz & 63;         // 0..63

    const __hip_bfloat16* Abase = A  + (size_t)bm * 256 * KDIM;
    const __hip_bfloat16* Bbase = Wb + (size_t)bn * 256 * KDIM;

    // --- staging source offsets (inverse-swizzled global, linear LDS dest) ---
    const int c0  = wid * 64 + lane;          // chunk 0..511
    const int c1  = 512 + c0;                 // chunk 512..1023
    const int cs0 = c0 ^ ((c0 >> 3) & 7);
    const int cs1 = c1 ^ ((c1 >> 3) & 7);
    const int gOff0 = (cs0 >> 2) * KDIM + (cs0 & 3) * 8;   // elements
    const int gOff1 = (cs1 >> 2) * KDIM + (cs1 & 3) * 8;
    const int lOff0 = wid * 1024;                          // bytes (wave-uniform)
    const int lOff1 = 8192 + wid * 1024;

    // --- swizzled ds_read byte offsets within a 16 KB slot (R2 map, 0-conflict) ---
    const int rsel = lane & 15;
    const int kby  = (lane >> 4) * 16;
    int offA[8], offB[4];
#pragma unroll
    for (int m = 0; m < 8; ++m) {
        int a = (wr * 128 + m * 16 + rsel) * 64 + kby;
        offA[m] = a ^ (((a >> 7) & 7) << 4);
    }
#pragma unroll
    for (int n = 0; n < 4; ++n) {
        int a = (wc * 64 + n * 16 + rsel) * 64 + kby;
        offB[n] = a ^ (((a >> 7) & 7) << 4);
    }

    f32x4 acc[8][4];
#pragma unroll
    for (int m = 0; m < 8; ++m)
#pragma unroll
        for (int n = 0; n < 4; ++n)
            acc[m][n] = (f32x4){0.f, 0.f, 0.f, 0.f};

    bf16x8 af0, af1, af2, af3, bf0, bf1, bf2, bf3;

    // --- prologue: stage tile 0 -> buf0 (8 gloads/wave) ---
    STAGE(Abase,  0, 0, 0);
    STAGE(Bbase,  0, 0, 1);
    STAGE(Abase, 32, 0, 2);
    STAGE(Bbase, 32, 0, 3);
    W0;
    __builtin_amdgcn_s_barrier();

    // --- main loop: KDIM/64 = 32 tiles, one span each ---
    for (int t = 0; t < 30; t += 2) {
        SPAN(t,     0, 1, W0);
        SPAN(t + 1, 1, 1, W0);
    }
    SPAN(30, 0, 1, W0);
    SPAN(31, 1, 0, WN);

    // --- epilogue: C/D layout col = lane&15, row = (lane>>4)*4 + r ---
    const int col0 = lane & 15;
    const int r0   = (lane >> 4) * 4;
#pragma unroll
    for (int n = 0; n < 4; ++n) {
        const int cg = bn * 256 + wc * 64 + n * 16 + col0;
        const float bv = bias[cg];
#pragma unroll
        for (int m = 0; m < 8; ++m) {
            const size_t rg = (size_t)bm * 256 + wr * 128 + m * 16 + r0;
#pragma unroll
            for (int r = 0; r < 4; ++r)
                C[(rg + r) * NDIM + cg] = acc[m][n][r] + bv;
        }
    }
}

// ---------------------------------------------------------------------------
// Fallback: naive fused fp32 GEMM (only if workspace too small).
// ---------------------------------------------------------------------------
__global__ void naive_kernel(const float* __restrict__ x,
                             const float* __restrict__ leaf,
                             const float* __restrict__ W,
                             const float* __restrict__ bias,
                             float* __restrict__ out) {
    long idx = (long)blockIdx.x * blockDim.x + threadIdx.x;
    if (idx >= (long)MROWS * NDIM) return;
    int  o = (int)(idx % NDIM);
    long m = idx / NDIM;
    int o2 = o / 169, o1 = (o / 13) % 13, o0 = o % 13;
    float acc = 0.f;
    for (int i = 0; i < KDIM; ++i) {
        int i2 = i / 169, i1 = (i / 13) % 13, i0 = i % 13;
        float d = 0.f;
#pragma unroll
        for (int r = 0; r < RANKD; ++r)
            d += leaf[( r     * LEAFD + o2) * LEAFD + i2]
               * leaf[((4 + r) * LEAFD + o1) * LEAFD + i1]
               * leaf[((8 + r) * LEAFD + o0) * LEAFD + i0];
        acc += x[m * KDIM + i] * (W[(long)o * KDIM + i] + d);
    }
    out[idx] = acc + bias[o];
}

// ---------------------------------------------------------------------------
extern "C" void kernel_launch(void* const* d_in, const int* in_sizes, int n_in,
                              void* d_out, int out_size, void* d_ws, size_t ws_size,
                              hipStream_t stream) {
    const float* x      = (const float*)d_in[0];
    const float* leaf   = (const float*)d_in[1];
    const float* weight = (const float*)d_in[2];
    const float* bias   = (const float*)d_in[3];
    float* out = (float*)d_out;

    const size_t needA = (size_t)MROWS * KDIM * sizeof(__hip_bfloat16);  // 64 MiB
    const size_t needW = (size_t)NDIM  * KDIM * sizeof(__hip_bfloat16);  // 8 MiB

    if (ws_size >= needA + needW) {
        __hip_bfloat16* xb = (__hip_bfloat16*)d_ws;
        __hip_bfloat16* wb = (__hip_bfloat16*)((char*)d_ws + needA);
        prep_kernel<<<16384 + 2048, 256, 0, stream>>>(x, leaf, weight, xb, wb);
        gemm12_kernel<<<(MROWS / 256) * (NDIM / 256), 512, 0, stream>>>(xb, wb, bias, out);
    } else {
        long total = (long)MROWS * NDIM;
        naive_kernel<<<(int)((total + 255) / 256), 256, 0, stream>>>(x, leaf, weight, bias, out);
    }
}

// Round 17
// 202.403 us; speedup vs baseline: 1.0800x; 1.0259x over previous
//
#include <hip/hip_runtime.h>
#include <hip/hip_bf16.h>
#include <stdint.h>

#define MROWS 16384   // B*S
#define KDIM  2048
#define NDIM  2048
#define LEAFD 13
#define RANKD 4

typedef __bf16 bf16x8 __attribute__((ext_vector_type(8)));
typedef float  f32x4  __attribute__((ext_vector_type(4)));

// ---------------------------------------------------------------------------
// Kernel 1 (merged prep): blocks [0,2048) convert x fp32->bf16 (grid-stride,
// 8 floats/thread — the ~32us BW-bound long pole, scheduled FIRST); blocks
// [2048, 2048+16384) build w_bf (tiny, fills in behind).
// ---------------------------------------------------------------------------
__global__ void prep_kernel(const float* __restrict__ x,
                            const float* __restrict__ leaf,
                            const float* __restrict__ weight,
                            __hip_bfloat16* __restrict__ xb,
                            __hip_bfloat16* __restrict__ wbf) {
    const int bid = blockIdx.x;
    if (bid < 2048) {
        const long n = (long)MROWS * KDIM;
        const long stride = (long)2048 * 256 * 8;
        for (long idx = ((long)bid * 256 + threadIdx.x) * 8; idx < n; idx += stride) {
            float4 v0 = *reinterpret_cast<const float4*>(x + idx);
            float4 v1 = *reinterpret_cast<const float4*>(x + idx + 4);
            __hip_bfloat16 tmp[8];
            tmp[0] = __float2bfloat16(v0.x); tmp[1] = __float2bfloat16(v0.y);
            tmp[2] = __float2bfloat16(v0.z); tmp[3] = __float2bfloat16(v0.w);
            tmp[4] = __float2bfloat16(v1.x); tmp[5] = __float2bfloat16(v1.y);
            tmp[6] = __float2bfloat16(v1.z); tmp[7] = __float2bfloat16(v1.w);
            *reinterpret_cast<uint4*>(xb + idx) = *reinterpret_cast<const uint4*>(tmp);
        }
    } else {
        __shared__ float ll[3 * RANKD * LEAFD * LEAFD];
        for (int t = threadIdx.x; t < 3 * RANKD * LEAFD * LEAFD; t += blockDim.x)
            ll[t] = leaf[t];
        __syncthreads();
        int idx = (bid - 2048) * 256 + threadIdx.x;
        int o = idx / KDIM, i = idx % KDIM;
        int o2 = o / 169, o1 = (o / 13) % 13, o0 = o % 13;
        int i2 = i / 169, i1 = (i / 13) % 13, i0 = i % 13;
        float d = 0.f;
#pragma unroll
        for (int r = 0; r < RANKD; ++r) {
            float a = ll[( r            * LEAFD + o2) * LEAFD + i2];
            float b = ll[((RANKD   + r) * LEAFD + o1) * LEAFD + i1];
            float c = ll[((2*RANKD + r) * LEAFD + o0) * LEAFD + i0];
            d += a * b * c;
        }
        wbf[idx] = __float2bfloat16(weight[idx] + d);
    }
}

// ---------------------------------------------------------------------------
// Kernel 2: R2's gemm8_kernel VERBATIM — the measured basin minimum
// (140.4-141.7 us, MfmaUtil ~43%, SQ_LDS_BANK_CONFLICT = 0).
// 256x256 tile, BK=64, 16x16x32 MFMA, 8 waves (2Mx4N), 8 phases / 2 K-tiles,
// 2buf x 4slot LDS (128KB), involution swizzle both-sides, vmcnt(4) at p3.
// ---------------------------------------------------------------------------

__device__ __forceinline__ void gload16(const __hip_bfloat16* g, char* l) {
    __builtin_amdgcn_global_load_lds((const __attribute__((address_space(1))) void*)g,
                                     (__attribute__((address_space(3))) void*)l,
                                     16, 0, 0);
}

#define STAGE(base, kb, bufi, slot) do {                                          \
    gload16((base) + (kb) + gOff0, smemc + (bufi)*65536 + (slot)*16384 + lOff0);  \
    gload16((base) + (kb) + gOff1, smemc + (bufi)*65536 + (slot)*16384 + lOff1);  \
} while (0)

#define LOAD_A(mh, kk, bufc)                                                        \
    af0 = *(const bf16x8*)(smemc + (bufc)*65536 + (kk)*32768 + offA[(mh)*4+0]);     \
    af1 = *(const bf16x8*)(smemc + (bufc)*65536 + (kk)*32768 + offA[(mh)*4+1]);     \
    af2 = *(const bf16x8*)(smemc + (bufc)*65536 + (kk)*32768 + offA[(mh)*4+2]);     \
    af3 = *(const bf16x8*)(smemc + (bufc)*65536 + (kk)*32768 + offA[(mh)*4+3]);

#define LOAD_B(kk, bufc)                                                                    \
    bf0 = *(const bf16x8*)(smemc + (bufc)*65536 + (kk)*32768 + 16384 + offB[0]);            \
    bf1 = *(const bf16x8*)(smemc + (bufc)*65536 + (kk)*32768 + 16384 + offB[1]);            \
    bf2 = *(const bf16x8*)(smemc + (bufc)*65536 + (kk)*32768 + 16384 + offB[2]);            \
    bf3 = *(const bf16x8*)(smemc + (bufc)*65536 + (kk)*32768 + 16384 + offB[3]);

#define MFMA_Q(mh) do {                                                                   \
    acc[(mh)*4+0][0] = __builtin_amdgcn_mfma_f32_16x16x32_bf16(af0, bf0, acc[(mh)*4+0][0], 0,0,0); \
    acc[(mh)*4+1][0] = __builtin_amdgcn_mfma_f32_16x16x32_bf16(af1, bf0, acc[(mh)*4+1][0], 0,0,0); \
    acc[(mh)*4+2][0] = __builtin_amdgcn_mfma_f32_16x16x32_bf16(af2, bf0, acc[(mh)*4+2][0], 0,0,0); \
    acc[(mh)*4+3][0] = __builtin_amdgcn_mfma_f32_16x16x32_bf16(af3, bf0, acc[(mh)*4+3][0], 0,0,0); \
    acc[(mh)*4+0][1] = __builtin_amdgcn_mfma_f32_16x16x32_bf16(af0, bf1, acc[(mh)*4+0][1], 0,0,0); \
    acc[(mh)*4+1][1] = __builtin_amdgcn_mfma_f32_16x16x32_bf16(af1, bf1, acc[(mh)*4+1][1], 0,0,0); \
    acc[(mh)*4+2][1] = __builtin_amdgcn_mfma_f32_16x16x32_bf16(af2, bf1, acc[(mh)*4+2][1], 0,0,0); \
    acc[(mh)*4+3][1] = __builtin_amdgcn_mfma_f32_16x16x32_bf16(af3, bf1, acc[(mh)*4+3][1], 0,0,0); \
    acc[(mh)*4+0][2] = __builtin_amdgcn_mfma_f32_16x16x32_bf16(af0, bf2, acc[(mh)*4+0][2], 0,0,0); \
    acc[(mh)*4+1][2] = __builtin_amdgcn_mfma_f32_16x16x32_bf16(af1, bf2, acc[(mh)*4+1][2], 0,0,0); \
    acc[(mh)*4+2][2] = __builtin_amdgcn_mfma_f32_16x16x32_bf16(af2, bf2, acc[(mh)*4+2][2], 0,0,0); \
    acc[(mh)*4+3][2] = __builtin_amdgcn_mfma_f32_16x16x32_bf16(af3, bf2, acc[(mh)*4+3][2], 0,0,0); \
    acc[(mh)*4+0][3] = __builtin_amdgcn_mfma_f32_16x16x32_bf16(af0, bf3, acc[(mh)*4+0][3], 0,0,0); \
    acc[(mh)*4+1][3] = __builtin_amdgcn_mfma_f32_16x16x32_bf16(af1, bf3, acc[(mh)*4+1][3], 0,0,0); \
    acc[(mh)*4+2][3] = __builtin_amdgcn_mfma_f32_16x16x32_bf16(af2, bf3, acc[(mh)*4+2][3], 0,0,0); \
    acc[(mh)*4+3][3] = __builtin_amdgcn_mfma_f32_16x16x32_bf16(af3, bf3, acc[(mh)*4+3][3], 0,0,0); \
} while (0)

#define BARRIER_IN do {                                     \
    __builtin_amdgcn_sched_barrier(0);                      \
    __builtin_amdgcn_s_barrier();                           \
    asm volatile("s_waitcnt lgkmcnt(0)" ::: "memory");      \
    __builtin_amdgcn_sched_barrier(0);                      \
    __builtin_amdgcn_s_setprio(1);                          \
} while (0)

#define BARRIER_OUT do {                                    \
    __builtin_amdgcn_s_setprio(0);                          \
    __builtin_amdgcn_sched_barrier(0);                      \
    __builtin_amdgcn_s_barrier();                           \
    __builtin_amdgcn_sched_barrier(0);                      \
} while (0)

#define WAIT4 asm volatile("s_waitcnt vmcnt(4)" ::: "memory")
#define WAIT0 asm volatile("s_waitcnt vmcnt(0)" ::: "memory")
#define WNONE do {} while (0)

// One K-tile = 4 phases (R2 cadence: single vmcnt(4) at p3).
#define KTILE(t, bufc, S0, S1, S2, S3, W3) do {                     \
    /* p0: (mh0,k0) */                                              \
    LOAD_B(0, bufc); LOAD_A(0, 0, bufc);                            \
    if (S0) STAGE(Abase, ((t)+1)*64+32, (bufc)^1, 2);               \
    BARRIER_IN; MFMA_Q(0); BARRIER_OUT;                             \
    /* p1: (mh1,k0) */                                              \
    LOAD_A(1, 0, bufc);                                             \
    if (S1) STAGE(Bbase, ((t)+1)*64+32, (bufc)^1, 3);               \
    BARRIER_IN; MFMA_Q(1); BARRIER_OUT;                             \
    /* p2: (mh0,k1) */                                              \
    LOAD_B(1, bufc); LOAD_A(0, 1, bufc);                            \
    if (S2) STAGE(Abase, ((t)+2)*64, (bufc), 0);                    \
    BARRIER_IN; MFMA_Q(0); BARRIER_OUT;                             \
    /* p3: (mh1,k1) */                                              \
    LOAD_A(1, 1, bufc);                                             \
    if (S3) STAGE(Bbase, ((t)+2)*64, (bufc), 1);                    \
    W3;                                                             \
    BARRIER_IN; MFMA_Q(1); BARRIER_OUT;                             \
} while (0)

__global__ __launch_bounds__(512, 2) void gemm8_kernel(const __hip_bfloat16* __restrict__ A,
                                                       const __hip_bfloat16* __restrict__ Wb,
                                                       const float* __restrict__ bias,
                                                       float* __restrict__ C) {
    __shared__ __align__(16) __hip_bfloat16 smem[2][4][8192];  // 128 KiB
    char* smemc = (char*)&smem[0][0][0];

    const int tid  = threadIdx.x;
    const int lane = tid & 63;
    const int wid  = tid >> 6;        // 0..7
    const int wr   = wid >> 2;        // 0..1  (M half)
    const int wc   = wid & 3;         // 0..3  (N quarter)

    // T1: XCD-aware swizzle (nwg=512, 512%8==0 -> bijective).
    const int bid = blockIdx.x;
    const int swz = (bid & 7) * 64 + (bid >> 3);
    const int bn  = swz >> 6;         // 0..7
    const int bm  = swz & 63;         // 0..63

    const __hip_bfloat16* Abase = A  + (size_t)bm * 256 * KDIM;
    const __hip_bfloat16* Bbase = Wb + (size_t)bn * 256 * KDIM;

    // --- staging source offsets (inverse-swizzled global, linear LDS dest) ---
    const int c0  = wid * 64 + lane;
    const int c1  = 512 + wid * 64 + lane;
    const int cs0 = c0 ^ ((c0 >> 3) & 7);
    const int cs1 = c1 ^ ((c1 >> 3) & 7);
    const int gOff0 = (cs0 >> 2) * KDIM + (cs0 & 3) * 8;   // elements
    const int gOff1 = (cs1 >> 2) * KDIM + (cs1 & 3) * 8;
    const int lOff0 = wid * 1024;                          // bytes (wave-uniform)
    const int lOff1 = 8192 + wid * 1024;

    // --- swizzled ds_read byte offsets within a 16 KB slot ---
    const int rsel = lane & 15;
    const int kby  = (lane >> 4) * 16;
    int offA[8], offB[4];
#pragma unroll
    for (int m = 0; m < 8; ++m) {
        int a = (wr * 128 + m * 16 + rsel) * 64 + kby;
        offA[m] = a ^ (((a >> 7) & 7) << 4);
    }
#pragma unroll
    for (int n = 0; n < 4; ++n) {
        int a = (wc * 64 + n * 16 + rsel) * 64 + kby;
        offB[n] = a ^ (((a >> 7) & 7) << 4);
    }

    f32x4 acc[8][4];
#pragma unroll
    for (int m = 0; m < 8; ++m)
#pragma unroll
        for (int n = 0; n < 4; ++n)
            acc[m][n] = (f32x4){0.f, 0.f, 0.f, 0.f};

    bf16x8 af0, af1, af2, af3, bf0, bf1, bf2, bf3;

    // --- prologue: stage 6 half-tiles (tile0 all 4 slots + tile1 slots 0,1) ---
    STAGE(Abase,  0, 0, 0);
    STAGE(Bbase,  0, 0, 1);
    STAGE(Abase, 32, 0, 2);
    STAGE(Bbase, 32, 0, 3);
    STAGE(Abase, 64, 1, 0);
    STAGE(Bbase, 64, 1, 1);
    WAIT4;                    // tile0 fully landed; h4,h5 may stay in flight
    __builtin_amdgcn_sched_barrier(0);
    __builtin_amdgcn_s_barrier();
    __builtin_amdgcn_sched_barrier(0);

    // --- main loop: KDIM/64 = 32 K-tiles, 2 per iteration ---
    for (int tt = 0; tt < 30; tt += 2) {
        KTILE(tt,     0, 1, 1, 1, 1, WAIT4);
        KTILE(tt + 1, 1, 1, 1, 1, 1, WAIT4);
    }
    KTILE(30, 0, 1, 1, 0, 0, WAIT0);   // stages h126,h127 (tile31 khi); drain
    KTILE(31, 1, 0, 0, 0, 0, WNONE);

    // --- epilogue: C/D layout col = lane&15, row = (lane>>4)*4 + r ---
    const int col0 = lane & 15;
    const int r0   = (lane >> 4) * 4;
#pragma unroll
    for (int n = 0; n < 4; ++n) {
        const int cg = bn * 256 + wc * 64 + n * 16 + col0;
        const float bv = bias[cg];
#pragma unroll
        for (int m = 0; m < 8; ++m) {
            const size_t rg = (size_t)bm * 256 + wr * 128 + m * 16 + r0;
#pragma unroll
            for (int r = 0; r < 4; ++r)
                C[(rg + r) * NDIM + cg] = acc[m][n][r] + bv;
        }
    }
}

// ---------------------------------------------------------------------------
// Fallback: naive fused fp32 GEMM (only if workspace too small).
// ---------------------------------------------------------------------------
__global__ void naive_kernel(const float* __restrict__ x,
                             const float* __restrict__ leaf,
                             const float* __restrict__ W,
                             const float* __restrict__ bias,
                             float* __restrict__ out) {
    long idx = (long)blockIdx.x * blockDim.x + threadIdx.x;
    if (idx >= (long)MROWS * NDIM) return;
    int  o = (int)(idx % NDIM);
    long m = idx / NDIM;
    int o2 = o / 169, o1 = (o / 13) % 13, o0 = o % 13;
    float acc = 0.f;
    for (int i = 0; i < KDIM; ++i) {
        int i2 = i / 169, i1 = (i / 13) % 13, i0 = i % 13;
        float d = 0.f;
#pragma unroll
        for (int r = 0; r < RANKD; ++r)
            d += leaf[( r     * LEAFD + o2) * LEAFD + i2]
               * leaf[((4 + r) * LEAFD + o1) * LEAFD + i1]
               * leaf[((8 + r) * LEAFD + o0) * LEAFD + i0];
        acc += x[m * KDIM + i] * (W[(long)o * KDIM + i] + d);
    }
    out[idx] = acc + bias[o];
}

// ---------------------------------------------------------------------------
extern "C" void kernel_launch(void* const* d_in, const int* in_sizes, int n_in,
                              void* d_out, int out_size, void* d_ws, size_t ws_size,
                              hipStream_t stream) {
    const float* x      = (const float*)d_in[0];
    const float* leaf   = (const float*)d_in[1];
    const float* weight = (const float*)d_in[2];
    const float* bias   = (const float*)d_in[3];
    float* out = (float*)d_out;

    const size_t needA = (size_t)MROWS * KDIM * sizeof(__hip_bfloat16);  // 64 MiB
    const size_t needW = (size_t)NDIM  * KDIM * sizeof(__hip_bfloat16);  // 8 MiB

    if (ws_size >= needA + needW) {
        __hip_bfloat16* xb = (__hip_bfloat16*)d_ws;
        __hip_bfloat16* wb = (__hip_bfloat16*)((char*)d_ws + needA);
        prep_kernel<<<2048 + 16384, 256, 0, stream>>>(x, leaf, weight, xb, wb);
        gemm8_kernel<<<(MROWS / 256) * (NDIM / 256), 512, 0, stream>>>(xb, wb, bias, out);
    } else {
        long total = (long)MROWS * NDIM;
        naive_kernel<<<(int)((total + 255) / 256), 256, 0, stream>>>(x, leaf, weight, bias, out);
    }
}